// Round 6
// baseline (321.146 us; speedup 1.0000x reference)
//
#include <hip/hip_runtime.h>
#include <hip/hip_bf16.h>

#define N_NODES 50000
#define N_EDGES 800000
#define CAP 64                              // max deg ~45 for Poisson(16) over 50K
#define NODE_GS_BLOCKS 1250                 // node-role blocks (grid-stride, 5 batches)
#define FILM_BLOCKS ((N_EDGES + 256) / 256) // 3126 (covers dummy e == N_EDGES)

__device__ __forceinline__ unsigned short f2bf(float f) {
    union { float f; unsigned u; } t; t.f = f;
    unsigned r = t.u + 0x7FFF + ((t.u >> 16) & 1);   // RNE
    return (unsigned short)(r >> 16);
}

// ---------------------------------------------------------------------------
// Fused prep kernel. Block-uniform role split.
//  node role (blocks 0..1249): weights staged in LDS ONCE, then 5 batches of
//    8 nodes each (grid-stride) — amortizes the 40 KB staging 5x.
//    ysvh[n][u] = packed bf16 {ys, yvx, yvy, yvz}  (8 B per channel u)
//    out[n]    = f32 [sc_s(32) | sc_v (w*3+i)(96)]
//  film role: FiLM hidden layer + reverse-CSR bucket build.
//    rec[e] = [h'0..7 | a0 a1x a1y a1z] (48 B), h' = silu(pre)*inv_sqrt8
//    bucket[dst][slot] = (e, src);  rec[N_EDGES] = zeros (agg tail padding)
// ---------------------------------------------------------------------------
__global__ __launch_bounds__(256) void prep_kernel(
    const float* __restrict__ x, const float* __restrict__ attr,
    const float* __restrict__ W1s, const float* __restrict__ W1v,
    const float* __restrict__ Wscs, const float* __restrict__ Wscv,
    const float* __restrict__ ee, const float* __restrict__ eattr,
    const int* __restrict__ eidx, const float* __restrict__ fcw1,
    int* __restrict__ counts, int2* __restrict__ bucket,
    float* __restrict__ rec,
    unsigned short* __restrict__ ysvh, float* __restrict__ out)
{
    // layout: x[0..1023] | W1s[1024..2047] | W1v[2048..3071]
    //         Wscs[3072..7167] | Wscv[7168..11263]        (44 KB total)
    __shared__ float shm[11264];
    const int tid = threadIdx.x;

    if (blockIdx.x < NODE_GS_BLOCKS) {
        // ---------------- node role ----------------
        ((float4*)(shm + 1024))[tid] = ((const float4*)W1s)[tid];
        ((float4*)(shm + 2048))[tid] = ((const float4*)W1v)[tid];
        #pragma unroll
        for (int i = 0; i < 4; ++i) {
            ((float4*)(shm + 3072))[tid + i*256] = ((const float4*)Wscs)[tid + i*256];
            ((float4*)(shm + 7168))[tid + i*256] = ((const float4*)Wscv)[tid + i*256];
        }

        const int nl = tid >> 5;
        const int w  = tid & 31;
        const float l1n = 0.17677669529663687f;   // 1/sqrt(32)
        const float scn = 0.08838834764831843f;   // 1/sqrt(128)

        for (int batch = 0; batch < 5; ++batch) {
            const int node0 = blockIdx.x * 40 + batch * 8;
            __syncthreads();   // protect shm x-region (and cover weight staging)
            ((float4*)shm)[tid] = ((const float4*)(x + (long)node0 * 128))[tid];
            __syncthreads();

            const int node = node0 + nl;
            const float* at = attr + (long)node * 4;
            int sp = 0;
            if (at[1] > 0.5f) sp = 1;
            if (at[2] > 0.5f) sp = 2;
            if (at[3] > 0.5f) sp = 3;

            const float* lx   = shm + nl * 128;
            const float* l1s  = shm + 1024;
            const float* l1v  = shm + 2048;
            const float* lscs = shm + 3072 + sp * 32;
            const float* lscv = shm + 7168 + sp * 32;

            float ys = 0.f, yv0 = 0.f, yv1 = 0.f, yv2 = 0.f;
            float ss = 0.f, sv0 = 0.f, sv1 = 0.f, sv2 = 0.f;
            #pragma unroll 8
            for (int u = 0; u < 32; ++u) {
                const float xs = lx[u];
                const float x0 = lx[32 + 3*u + 0];
                const float x1 = lx[32 + 3*u + 1];
                const float x2 = lx[32 + 3*u + 2];
                const float w1s = l1s[u*32 + w];
                const float w1v = l1v[u*32 + w];
                const float wss = lscs[u*128 + w];
                const float wsv = lscv[u*128 + w];
                ys  += xs * w1s;
                yv0 += x0 * w1v;  yv1 += x1 * w1v;  yv2 += x2 * w1v;
                ss  += xs * wss;
                sv0 += x0 * wsv;  sv1 += x1 * wsv;  sv2 += x2 * wsv;
            }

            uint2 pk;
            pk.x = (unsigned)f2bf(ys  * l1n) | ((unsigned)f2bf(yv0 * l1n) << 16);
            pk.y = (unsigned)f2bf(yv1 * l1n) | ((unsigned)f2bf(yv2 * l1n) << 16);
            *(uint2*)(ysvh + (long)node * 128 + w * 4) = pk;

            float* op = out + (long)node * 128;
            op[w] = ss * scn;
            op[32 + 3*w + 0] = sv0 * scn;
            op[32 + 3*w + 1] = sv1 * scn;
            op[32 + 3*w + 2] = sv2 * scn;
        }
    } else {
        // ---------------- film/bucket role ----------------
        if (tid < 64) shm[tid] = fcw1[tid];
        __syncthreads();

        const int e = (blockIdx.x - NODE_GS_BLOCKS) * 256 + tid;
        if (e < N_EDGES) {
            const float4 ea = ((const float4*)(ee + (long)e * 8))[0];
            const float4 eb = ((const float4*)(ee + (long)e * 8))[1];
            const float eev[8] = {ea.x, ea.y, ea.z, ea.w, eb.x, eb.y, eb.z, eb.w};
            const float inv_sqrt8 = 0.35355339059327373f;
            float h[8];
            #pragma unroll
            for (int j = 0; j < 8; ++j) {
                float pre = 0.f;
                #pragma unroll
                for (int b = 0; b < 8; ++b) pre += eev[b] * shm[b*8 + j];
                pre *= inv_sqrt8;
                h[j] = pre / (1.f + __expf(-pre)) * inv_sqrt8;
            }
            float* rp = rec + (long)e * 12;
            ((float4*)rp)[0] = make_float4(h[0], h[1], h[2], h[3]);
            ((float4*)rp)[1] = make_float4(h[4], h[5], h[6], h[7]);
            ((float4*)rp)[2] = ((const float4*)eattr)[e];

            const int src = eidx[e];
            const int dst = eidx[N_EDGES + e];
            const int slot = atomicAdd(&counts[dst], 1);
            if (slot < CAP) bucket[(long)dst * CAP + slot] = make_int2(e, src);
        } else if (e == N_EDGES) {
            float* rp = rec + (long)e * 12;
            ((float4*)rp)[0] = make_float4(0.f, 0.f, 0.f, 0.f);
            ((float4*)rp)[1] = make_float4(0.f, 0.f, 0.f, 0.f);
            ((float4*)rp)[2] = make_float4(0.f, 0.f, 0.f, 0.f);
        }
    }
}

// ---------------------------------------------------------------------------
// Aggregation: 4 nodes / 256-thread block, ONE WAVE (64 lanes) per node.
// half 0 (lanes 0..31) processes even bucket slots, half 1 odd slots — no
// intra-wave divergence, no phase-B, one bucket row per wave. Halves merge
// with __shfl_xor(32); epilogue splits: half0 -> {scalar, vec-x}, half1 ->
// {vec-y, vec-z} with uniform pointer-selected code. W2 staged in LDS.
// ---------------------------------------------------------------------------
__global__ __launch_bounds__(256) void agg_kernel(
    const float* __restrict__ fcw2,
    const float* __restrict__ W2s, const float* __restrict__ W2v,
    const unsigned short* __restrict__ ysvh,
    const int* __restrict__ counts, const int2* __restrict__ bucket,
    const float* __restrict__ rec,
    float* __restrict__ out)
{
    __shared__ float w2s[2048];   // 8 KB
    __shared__ float w2v[2048];   // 8 KB

    const int tid = threadIdx.x;
    for (int i = tid; i < 2048; i += 256) { w2s[i] = W2s[i]; w2v[i] = W2v[i]; }
    __syncthreads();

    const int nl   = tid >> 6;       // wave = node
    const int lane = tid & 63;
    const int u    = lane & 31;      // channel
    const int half = lane >> 5;      // 0: even slots, 1: odd slots
    const int node = blockIdx.x * 4 + nl;

    // fc2 fragment: f2r[j][q] = fcw2[j*128 + q*32 + u]
    float f2r[8][4];
    #pragma unroll
    for (int j = 0; j < 8; ++j) {
        f2r[j][0] = fcw2[j*128 + u];
        f2r[j][1] = fcw2[j*128 + 32 + u];
        f2r[j][2] = fcw2[j*128 + 64 + u];
        f2r[j][3] = fcw2[j*128 + 96 + u];
    }

    const int cnt = min(counts[node], CAP);
    int2 b = bucket[(long)node * CAP + lane];
    if (lane >= cnt) b = make_int2(N_EDGES, 0);   // dummy: zero record

    float msa = 0.f, msb = 0.f;
    float va0 = 0.f, va1 = 0.f, va2 = 0.f;
    float vb0 = 0.f, vb1 = 0.f, vb2 = 0.f;

    #define ACCUM(HA, HB, AT, Y)                                             \
    {                                                                        \
        const float es = __uint_as_float((Y).x << 16);                       \
        const float ex = __uint_as_float((Y).x & 0xffff0000u);               \
        const float ey = __uint_as_float((Y).y << 16);                       \
        const float ez = __uint_as_float((Y).y & 0xffff0000u);               \
        const float hh[8] = {HA.x,HA.y,HA.z,HA.w,HB.x,HB.y,HB.z,HB.w};       \
        float w00=0.f, w01=0.f, w10=0.f, w11=0.f;                            \
        _Pragma("unroll")                                                    \
        for (int j = 0; j < 8; ++j) {                                        \
            w00 += hh[j]*f2r[j][0]; w01 += hh[j]*f2r[j][1];                  \
            w10 += hh[j]*f2r[j][2]; w11 += hh[j]*f2r[j][3];                  \
        }                                                                    \
        const float a0 = AT.x, a1x = AT.y, a1y = AT.z, a1z = AT.w;           \
        msa += w00 * es * a0;                                                \
        msb += w11 * (ex*a1x + ey*a1y + ez*a1z);                             \
        const float t = w01 * es;                                            \
        va0 += t*a1x; va1 += t*a1y; va2 += t*a1z;                            \
        const float s = w10 * a0;                                            \
        vb0 += s*ex; vb1 += s*ey; vb2 += s*ez;                               \
    }

    #define FETCH(SLOT, RA, RB, RT, Y)                                       \
    {                                                                        \
        const int fe = __shfl(b.x, (SLOT), 64);                              \
        const int fs = __shfl(b.y, (SLOT), 64);                              \
        const float4* rp = (const float4*)(rec + (long)fe * 12);             \
        RA = rp[0]; RB = rp[1]; RT = rp[2];                                  \
        Y = *(const uint2*)(ysvh + (long)fs * 128 + u * 4);                  \
    }

    // 2-stage software pipeline; this half's slot at step k is k+half
    float4 cA, cB, cT; uint2 cy;
    FETCH(half, cA, cB, cT, cy)
    for (int k = 0; k < cnt; k += 2) {
        float4 nA, nB, nT; uint2 ny;
        int ns = k + 2 + half;
        if (ns > 63) ns = 63;        // clamp (slot >= cnt is dummy anyway)
        FETCH(ns, nA, nB, nT, ny)
        ACCUM(cA, cB, cT, cy)
        cA = nA; cB = nB; cT = nT; cy = ny;
    }
    #undef FETCH
    #undef ACCUM

    // merge even/odd halves: both halves end with full per-channel sums
    msa += __shfl_xor(msa, 32, 64);
    msb += __shfl_xor(msb, 32, 64);
    va0 += __shfl_xor(va0, 32, 64);
    va1 += __shfl_xor(va1, 32, 64);
    va2 += __shfl_xor(va2, 32, 64);
    vb0 += __shfl_xor(vb0, 32, 64);
    vb1 += __shfl_xor(vb1, 32, 64);
    vb2 += __shfl_xor(vb2, 32, 64);
    msb *= 0.5773502691896258f;  // INV_SQRT3

    // lin2 epilogue, uniform across halves:
    //   half0: A-dot over (msa,msb) x W2s -> out_s[u];  B-dot (va0,vb0) x W2v -> out_v[u].x
    //   half1: A-dot over (va1,vb1) x W2v -> out_v[u].y; B-dot (va2,vb2) x W2v -> out_v[u].z
    const float  pA = half ? va1 : msa;
    const float  pB = half ? vb1 : msb;
    const float  pC = half ? va2 : va0;
    const float  pD = half ? vb2 : vb0;
    const float* WA = half ? w2v : w2s;

    float A = 0.f, B = 0.f;
    #pragma unroll 8
    for (int q = 0; q < 32; ++q) {
        const float aq = __shfl(pA, q, 32);
        const float bq = __shfl(pB, q, 32);
        const float cq = __shfl(pC, q, 32);
        const float dq = __shfl(pD, q, 32);
        A += aq * WA[q*32 + u]  + bq * WA[(32 + q)*32 + u];
        B += cq * w2v[q*32 + u] + dq * w2v[(32 + q)*32 + u];
    }

    const float sc = 0.03125f;  // (1/sqrt 16) * (1/sqrt 64)
    float* op = out + (long)node * 128;
    const int ia = half ? (32 + 3*u + 1) : u;
    const int ib = half ? (32 + 3*u + 2) : (32 + 3*u + 0);
    op[ia] += A * sc;
    op[ib] += B * sc;
}

extern "C" void kernel_launch(void* const* d_in, const int* in_sizes, int n_in,
                              void* d_out, int out_size, void* d_ws, size_t ws_size,
                              hipStream_t stream) {
    const float* x     = (const float*)d_in[0];
    const float* attr  = (const float*)d_in[1];
    const float* ee    = (const float*)d_in[2];
    const float* eattr = (const float*)d_in[3];
    const int*   eidx  = (const int*)  d_in[4];
    const float* W1s   = (const float*)d_in[5];
    const float* W1v   = (const float*)d_in[6];
    const float* fcw1  = (const float*)d_in[7];
    const float* fcw2  = (const float*)d_in[8];
    const float* W2s   = (const float*)d_in[9];
    const float* W2v   = (const float*)d_in[10];
    const float* Wscs  = (const float*)d_in[11];
    const float* Wscv  = (const float*)d_in[12];

    float* out = (float*)d_out;

    // workspace layout (all offsets 16-B aligned)
    unsigned short* ysvh = (unsigned short*)d_ws;            // 50000*128 bf16 = 12.8 MB
    int*   counts = (int*)(ysvh + (long)N_NODES * 128);      // 50000 i32
    int2*  bucket = (int2*)(counts + N_NODES);               // 50000*64 int2 = 25.6 MB
    float* rec    = (float*)(bucket + (long)N_NODES * CAP);  // 800001*12 f32 = 38.4 MB

    hipMemsetAsync(counts, 0, N_NODES * sizeof(int), stream);
    prep_kernel<<<NODE_GS_BLOCKS + FILM_BLOCKS, 256, 0, stream>>>(
        x, attr, W1s, W1v, Wscs, Wscv, ee, eattr, eidx, fcw1,
        counts, bucket, rec, ysvh, out);
    agg_kernel<<<N_NODES/4, 256, 0, stream>>>(fcw2, W2s, W2v, ysvh,
                                              counts, bucket, rec, out);
}

// Round 7
// 285.708 us; speedup vs baseline: 1.1240x; 1.1240x over previous
//
#include <hip/hip_runtime.h>
#include <hip/hip_bf16.h>

#define N_NODES 50000
#define N_EDGES 800000
#define CAP 64                       // max deg ~45 for Poisson(16) over 50K
#define NODE_GS_BLOCKS 1250          // node-role blocks (grid-stride, 5 batches)
#define BUCKET_BLOCKS (N_EDGES/256)  // 3125 exact

__device__ __forceinline__ unsigned short f2bf(float f) {
    union { float f; unsigned u; } t; t.f = f;
    unsigned r = t.u + 0x7FFF + ((t.u >> 16) & 1);   // RNE
    return (unsigned short)(r >> 16);
}

// ---------------------------------------------------------------------------
// Prep kernel, role-split:
//  node role (blocks 0..1249): lin1 + self-connection, weights in LDS once,
//    5 grid-stride batches of 8 nodes.
//    ysvh[n][u] = packed bf16 {ys,yvx,yvy,yvz}; out[n] = sc (f32)
//  bucket role (blocks 1250..4374): reverse-CSR build only (no FiLM math).
//    bucket[dst][slot] = (e, src)
// ---------------------------------------------------------------------------
__global__ __launch_bounds__(256) void prep_kernel(
    const float* __restrict__ x, const float* __restrict__ attr,
    const float* __restrict__ W1s, const float* __restrict__ W1v,
    const float* __restrict__ Wscs, const float* __restrict__ Wscv,
    const int* __restrict__ eidx,
    int* __restrict__ counts, int2* __restrict__ bucket,
    unsigned short* __restrict__ ysvh, float* __restrict__ out)
{
    // node role layout: x[0..1023] | W1s | W1v | Wscs[3072..] | Wscv[7168..]
    __shared__ float shm[11264];
    const int tid = threadIdx.x;

    if (blockIdx.x < NODE_GS_BLOCKS) {
        // ---------------- node role ----------------
        ((float4*)(shm + 1024))[tid] = ((const float4*)W1s)[tid];
        ((float4*)(shm + 2048))[tid] = ((const float4*)W1v)[tid];
        #pragma unroll
        for (int i = 0; i < 4; ++i) {
            ((float4*)(shm + 3072))[tid + i*256] = ((const float4*)Wscs)[tid + i*256];
            ((float4*)(shm + 7168))[tid + i*256] = ((const float4*)Wscv)[tid + i*256];
        }

        const int nl = tid >> 5;
        const int w  = tid & 31;
        const float l1n = 0.17677669529663687f;   // 1/sqrt(32)
        const float scn = 0.08838834764831843f;   // 1/sqrt(128)

        for (int batch = 0; batch < 5; ++batch) {
            const int node0 = blockIdx.x * 40 + batch * 8;
            __syncthreads();   // protect shm x-region (covers weight staging too)
            ((float4*)shm)[tid] = ((const float4*)(x + (long)node0 * 128))[tid];
            __syncthreads();

            const int node = node0 + nl;
            const float* at = attr + (long)node * 4;
            int sp = 0;
            if (at[1] > 0.5f) sp = 1;
            if (at[2] > 0.5f) sp = 2;
            if (at[3] > 0.5f) sp = 3;

            const float* lx   = shm + nl * 128;
            const float* l1s  = shm + 1024;
            const float* l1v  = shm + 2048;
            const float* lscs = shm + 3072 + sp * 32;
            const float* lscv = shm + 7168 + sp * 32;

            float ys = 0.f, yv0 = 0.f, yv1 = 0.f, yv2 = 0.f;
            float ss = 0.f, sv0 = 0.f, sv1 = 0.f, sv2 = 0.f;
            #pragma unroll 8
            for (int u = 0; u < 32; ++u) {
                const float xs = lx[u];
                const float x0 = lx[32 + 3*u + 0];
                const float x1 = lx[32 + 3*u + 1];
                const float x2 = lx[32 + 3*u + 2];
                const float w1s = l1s[u*32 + w];
                const float w1v = l1v[u*32 + w];
                const float wss = lscs[u*128 + w];
                const float wsv = lscv[u*128 + w];
                ys  += xs * w1s;
                yv0 += x0 * w1v;  yv1 += x1 * w1v;  yv2 += x2 * w1v;
                ss  += xs * wss;
                sv0 += x0 * wsv;  sv1 += x1 * wsv;  sv2 += x2 * wsv;
            }

            uint2 pk;
            pk.x = (unsigned)f2bf(ys  * l1n) | ((unsigned)f2bf(yv0 * l1n) << 16);
            pk.y = (unsigned)f2bf(yv1 * l1n) | ((unsigned)f2bf(yv2 * l1n) << 16);
            *(uint2*)(ysvh + (long)node * 128 + w * 4) = pk;

            float* op = out + (long)node * 128;
            op[w] = ss * scn;
            op[32 + 3*w + 0] = sv0 * scn;
            op[32 + 3*w + 1] = sv1 * scn;
            op[32 + 3*w + 2] = sv2 * scn;
        }
    } else {
        // ---------------- bucket role (no FiLM, no rec) ----------------
        const int e = (blockIdx.x - NODE_GS_BLOCKS) * 256 + tid;
        const int src = eidx[e];
        const int dst = eidx[N_EDGES + e];
        const int slot = atomicAdd(&counts[dst], 1);
        if (slot < CAP) bucket[(long)dst * CAP + slot] = make_int2(e, src);
    }
}

// ---------------------------------------------------------------------------
// Aggregation (round-5 skeleton): 8 nodes / 256-thread block, 32 lanes per
// node-group, 2 groups per wave. NEW: FiLM computed IN-KERNEL, lane-parallel —
// lane u computes h' for its own bucket slot u in the prologue and caches
// {h'0..7, a0,a1x,a1y,a1z} in LDS. Loop body reads it via wave-uniform
// broadcast ds_read_b128 (free); only the 2 prefetched ysv gathers hit global.
// No barriers anywhere (all LDS traffic is intra-wave).
// ---------------------------------------------------------------------------
__global__ __launch_bounds__(256) void agg_kernel(
    const float* __restrict__ ee, const float* __restrict__ eattr,
    const float* __restrict__ fcw1, const float* __restrict__ fcw2,
    const float* __restrict__ W2s, const float* __restrict__ W2v,
    const unsigned short* __restrict__ ysvh,
    const int* __restrict__ counts, const int2* __restrict__ bucket,
    float* __restrict__ out)
{
    __shared__ float hrec[8][32 * 12];  // 12 KB: per group, per slot {h'[8], attr[4]}
    __shared__ float mid[8][256];       // 8 KB

    const int tid = threadIdx.x;
    const int nl = tid >> 5;
    const int u  = tid & 31;
    const int node = blockIdx.x * 8 + nl;
    const float inv_sqrt8 = 0.35355339059327373f;

    // fc2 fragment: f2r[j][q] = fcw2[j*128 + q*32 + u]
    float f2r[8][4];
    #pragma unroll
    for (int j = 0; j < 8; ++j) {
        f2r[j][0] = fcw2[j*128 + u];
        f2r[j][1] = fcw2[j*128 + 32 + u];
        f2r[j][2] = fcw2[j*128 + 64 + u];
        f2r[j][3] = fcw2[j*128 + 96 + u];
    }

    const int cnt = min(counts[node], CAP);
    int2 b0 = bucket[(long)node * CAP + u];
    const bool dummy = (u >= cnt);
    if (dummy) b0 = make_int2(0, 0);

    // ---- prologue: lane u computes FiLM h' for its own slot's edge ----
    {
        const float4 ea = ((const float4*)(ee + (long)b0.x * 8))[0];
        const float4 eb = ((const float4*)(ee + (long)b0.x * 8))[1];
        const float4 at = ((const float4*)eattr)[b0.x];
        const float eev[8] = {ea.x, ea.y, ea.z, ea.w, eb.x, eb.y, eb.z, eb.w};
        float* hr = hrec[nl] + u * 12;
        float h[8];
        #pragma unroll
        for (int j = 0; j < 8; ++j) {
            float pre = 0.f;
            #pragma unroll
            for (int b = 0; b < 8; ++b) pre += eev[b] * fcw1[b*8 + j];
            pre *= inv_sqrt8;
            const float s = pre / (1.f + __expf(-pre)) * inv_sqrt8;
            h[j] = dummy ? 0.f : s;     // h'=0 kills every term of a dummy slot
        }
        ((float4*)hr)[0] = make_float4(h[0], h[1], h[2], h[3]);
        ((float4*)hr)[1] = make_float4(h[4], h[5], h[6], h[7]);
        ((float4*)hr)[2] = at;
        // no barrier: written and read by the same 32-lane group (wave-sync)
    }

    float msa = 0.f, msb = 0.f;
    float va0 = 0.f, va1 = 0.f, va2 = 0.f;
    float vb0 = 0.f, vb1 = 0.f, vb2 = 0.f;

    #define ACCUM(HA, HB, AT, Y)                                             \
    {                                                                        \
        const float es = __uint_as_float((Y).x << 16);                       \
        const float ex = __uint_as_float((Y).x & 0xffff0000u);               \
        const float ey = __uint_as_float((Y).y << 16);                       \
        const float ez = __uint_as_float((Y).y & 0xffff0000u);               \
        const float hh[8] = {HA.x,HA.y,HA.z,HA.w,HB.x,HB.y,HB.z,HB.w};       \
        float w00=0.f, w01=0.f, w10=0.f, w11=0.f;                            \
        _Pragma("unroll")                                                    \
        for (int j = 0; j < 8; ++j) {                                        \
            w00 += hh[j]*f2r[j][0]; w01 += hh[j]*f2r[j][1];                  \
            w10 += hh[j]*f2r[j][2]; w11 += hh[j]*f2r[j][3];                  \
        }                                                                    \
        const float a0 = AT.x, a1x = AT.y, a1y = AT.z, a1z = AT.w;           \
        msa += w00 * es * a0;                                                \
        msb += w11 * (ex*a1x + ey*a1y + ez*a1z);                             \
        const float t = w01 * es;                                            \
        va0 += t*a1x; va1 += t*a1y; va2 += t*a1z;                            \
        const float s = w10 * a0;                                            \
        vb0 += s*ex; vb1 += s*ey; vb2 += s*ez;                               \
    }

    // ---- main loop: 2 edges/iter; ysv gathers prefetched one pair ahead ----
    const int c0 = min(cnt, 32);
    {
        int s0 = __shfl(b0.y, 0, 32);
        int s1 = __shfl(b0.y, 1, 32);
        uint2 y0 = *(const uint2*)(ysvh + (long)s0 * 128 + u * 4);
        uint2 y1 = *(const uint2*)(ysvh + (long)s1 * 128 + u * 4);
        for (int k = 0; k < c0; k += 2) {
            const int kn = (k + 2) & 31;            // wrap: dummy-safe
            const int sn0 = __shfl(b0.y, kn, 32);
            const int sn1 = __shfl(b0.y, kn + 1, 32);
            uint2 yn0 = *(const uint2*)(ysvh + (long)sn0 * 128 + u * 4);
            uint2 yn1 = *(const uint2*)(ysvh + (long)sn1 * 128 + u * 4);
            const float4* h0p = (const float4*)(hrec[nl] + k * 12);
            const float4* h1p = (const float4*)(hrec[nl] + (k + 1) * 12);
            const float4 A0 = h0p[0], B0 = h0p[1], T0 = h0p[2];
            const float4 A1 = h1p[0], B1 = h1p[1], T1 = h1p[2];
            ACCUM(A0, B0, T0, y0)
            ACCUM(A1, B1, T1, y1)
            y0 = yn0; y1 = yn1;
        }
    }

    // ---- rare tail (cnt > 32, ~1e-4 of nodes): redundant per-lane FiLM ----
    if (cnt > 32) {
        int2 b1 = bucket[(long)node * CAP + 32 + u];
        for (int k = 32; k < cnt; ++k) {
            const int e = __shfl(b1.x, k - 32, 32);
            const int s = __shfl(b1.y, k - 32, 32);
            const float4 ea = ((const float4*)(ee + (long)e * 8))[0];
            const float4 eb = ((const float4*)(ee + (long)e * 8))[1];
            const float4 at = ((const float4*)eattr)[e];
            const float eev[8] = {ea.x, ea.y, ea.z, ea.w, eb.x, eb.y, eb.z, eb.w};
            float4 HA, HB;
            float h[8];
            #pragma unroll
            for (int j = 0; j < 8; ++j) {
                float pre = 0.f;
                #pragma unroll
                for (int b = 0; b < 8; ++b) pre += eev[b] * fcw1[b*8 + j];
                pre *= inv_sqrt8;
                h[j] = pre / (1.f + __expf(-pre)) * inv_sqrt8;
            }
            HA = make_float4(h[0], h[1], h[2], h[3]);
            HB = make_float4(h[4], h[5], h[6], h[7]);
            const uint2 y = *(const uint2*)(ysvh + (long)s * 128 + u * 4);
            ACCUM(HA, HB, at, y)
        }
    }
    #undef ACCUM

    msb *= 0.5773502691896258f;  // INV_SQRT3

    // ---- lin2 epilogue via mid-LDS transpose (round-5 form, intra-group) ----
    float* m = mid[nl];
    m[u]       = msa;
    m[32 + u]  = msb;
    m[64  + u*3 + 0] = va0;  m[64  + u*3 + 1] = va1;  m[64  + u*3 + 2] = va2;
    m[160 + u*3 + 0] = vb0;  m[160 + u*3 + 1] = vb1;  m[160 + u*3 + 2] = vb2;

    float os = 0.f, ov0 = 0.f, ov1 = 0.f, ov2 = 0.f;
    #pragma unroll 8
    for (int q = 0; q < 32; ++q) {
        const float wsa = W2s[q*32 + u];
        const float wsb = W2s[(32 + q)*32 + u];
        os += m[q] * wsa + m[32 + q] * wsb;
        const float wva = W2v[q*32 + u];
        const float wvb = W2v[(32 + q)*32 + u];
        ov0 += m[64 + q*3 + 0] * wva + m[160 + q*3 + 0] * wvb;
        ov1 += m[64 + q*3 + 1] * wva + m[160 + q*3 + 1] * wvb;
        ov2 += m[64 + q*3 + 2] * wva + m[160 + q*3 + 2] * wvb;
    }

    const float sc = 0.03125f;  // (1/sqrt 16) * (1/sqrt 64)
    float* op = out + (long)node * 128;
    op[u]            += os  * sc;
    op[32 + 3*u + 0] += ov0 * sc;
    op[32 + 3*u + 1] += ov1 * sc;
    op[32 + 3*u + 2] += ov2 * sc;
}

extern "C" void kernel_launch(void* const* d_in, const int* in_sizes, int n_in,
                              void* d_out, int out_size, void* d_ws, size_t ws_size,
                              hipStream_t stream) {
    const float* x     = (const float*)d_in[0];
    const float* attr  = (const float*)d_in[1];
    const float* ee    = (const float*)d_in[2];
    const float* eattr = (const float*)d_in[3];
    const int*   eidx  = (const int*)  d_in[4];
    const float* W1s   = (const float*)d_in[5];
    const float* W1v   = (const float*)d_in[6];
    const float* fcw1  = (const float*)d_in[7];
    const float* fcw2  = (const float*)d_in[8];
    const float* W2s   = (const float*)d_in[9];
    const float* W2v   = (const float*)d_in[10];
    const float* Wscs  = (const float*)d_in[11];
    const float* Wscv  = (const float*)d_in[12];

    float* out = (float*)d_out;

    // workspace layout (16-B aligned)
    unsigned short* ysvh = (unsigned short*)d_ws;            // 50000*128 bf16 = 12.8 MB
    int*   counts = (int*)(ysvh + (long)N_NODES * 128);      // 50000 i32
    int2*  bucket = (int2*)(counts + N_NODES);               // 50000*64 int2 = 25.6 MB

    hipMemsetAsync(counts, 0, N_NODES * sizeof(int), stream);
    prep_kernel<<<NODE_GS_BLOCKS + BUCKET_BLOCKS, 256, 0, stream>>>(
        x, attr, W1s, W1v, Wscs, Wscv, eidx, counts, bucket, ysvh, out);
    agg_kernel<<<N_NODES/8, 256, 0, stream>>>(ee, eattr, fcw1, fcw2, W2s, W2v,
                                              ysvh, counts, bucket, out);
}

// Round 8
// 283.940 us; speedup vs baseline: 1.1310x; 1.0062x over previous
//
#include <hip/hip_runtime.h>
#include <hip/hip_bf16.h>

#define N_NODES 50000
#define N_EDGES 800000
#define CAP 64                       // max deg ~45 for Poisson(16) over 50K
#define NODE_GS_BLOCKS 1250          // node-role blocks (grid-stride, 5 batches)
#define BUCKET_BLOCKS (N_EDGES/256)  // 3125 exact

__device__ __forceinline__ unsigned short f2bf(float f) {
    union { float f; unsigned u; } t; t.f = f;
    unsigned r = t.u + 0x7FFF + ((t.u >> 16) & 1);   // RNE
    return (unsigned short)(r >> 16);
}

// ---------------------------------------------------------------------------
// Prep kernel, role-split:
//  node role (blocks 0..1249): lin1 + self-connection, weights in LDS once,
//    5 grid-stride batches of 8 nodes.
//    ysvh[n][u] = packed bf16 {ys,yvx,yvy,yvz}; out[n] = sc (f32)
//  bucket role: reverse-CSR build, edge id only (src resolved in agg).
// ---------------------------------------------------------------------------
__global__ __launch_bounds__(256) void prep_kernel(
    const float* __restrict__ x, const float* __restrict__ attr,
    const float* __restrict__ W1s, const float* __restrict__ W1v,
    const float* __restrict__ Wscs, const float* __restrict__ Wscv,
    const int* __restrict__ eidx,
    int* __restrict__ counts, int* __restrict__ bucket,
    unsigned short* __restrict__ ysvh, float* __restrict__ out)
{
    // node role layout: x[0..1023] | W1s | W1v | Wscs[3072..] | Wscv[7168..]
    __shared__ float shm[11264];
    const int tid = threadIdx.x;

    if (blockIdx.x < NODE_GS_BLOCKS) {
        // ---------------- node role ----------------
        ((float4*)(shm + 1024))[tid] = ((const float4*)W1s)[tid];
        ((float4*)(shm + 2048))[tid] = ((const float4*)W1v)[tid];
        #pragma unroll
        for (int i = 0; i < 4; ++i) {
            ((float4*)(shm + 3072))[tid + i*256] = ((const float4*)Wscs)[tid + i*256];
            ((float4*)(shm + 7168))[tid + i*256] = ((const float4*)Wscv)[tid + i*256];
        }

        const int nl = tid >> 5;
        const int w  = tid & 31;
        const float l1n = 0.17677669529663687f;   // 1/sqrt(32)
        const float scn = 0.08838834764831843f;   // 1/sqrt(128)

        for (int batch = 0; batch < 5; ++batch) {
            const int node0 = blockIdx.x * 40 + batch * 8;
            __syncthreads();   // protect shm x-region (covers weight staging too)
            ((float4*)shm)[tid] = ((const float4*)(x + (long)node0 * 128))[tid];
            __syncthreads();

            const int node = node0 + nl;
            const float* at = attr + (long)node * 4;
            int sp = 0;
            if (at[1] > 0.5f) sp = 1;
            if (at[2] > 0.5f) sp = 2;
            if (at[3] > 0.5f) sp = 3;

            const float* lx   = shm + nl * 128;
            const float* l1s  = shm + 1024;
            const float* l1v  = shm + 2048;
            const float* lscs = shm + 3072 + sp * 32;
            const float* lscv = shm + 7168 + sp * 32;

            float ys = 0.f, yv0 = 0.f, yv1 = 0.f, yv2 = 0.f;
            float ss = 0.f, sv0 = 0.f, sv1 = 0.f, sv2 = 0.f;
            #pragma unroll 8
            for (int u = 0; u < 32; ++u) {
                const float xs = lx[u];
                const float x0 = lx[32 + 3*u + 0];
                const float x1 = lx[32 + 3*u + 1];
                const float x2 = lx[32 + 3*u + 2];
                const float w1s = l1s[u*32 + w];
                const float w1v = l1v[u*32 + w];
                const float wss = lscs[u*128 + w];
                const float wsv = lscv[u*128 + w];
                ys  += xs * w1s;
                yv0 += x0 * w1v;  yv1 += x1 * w1v;  yv2 += x2 * w1v;
                ss  += xs * wss;
                sv0 += x0 * wsv;  sv1 += x1 * wsv;  sv2 += x2 * wsv;
            }

            uint2 pk;
            pk.x = (unsigned)f2bf(ys  * l1n) | ((unsigned)f2bf(yv0 * l1n) << 16);
            pk.y = (unsigned)f2bf(yv1 * l1n) | ((unsigned)f2bf(yv2 * l1n) << 16);
            *(uint2*)(ysvh + (long)node * 128 + w * 4) = pk;

            float* op = out + (long)node * 128;
            op[w] = ss * scn;
            op[32 + 3*w + 0] = sv0 * scn;
            op[32 + 3*w + 1] = sv1 * scn;
            op[32 + 3*w + 2] = sv2 * scn;
        }
    } else {
        // ---------------- bucket role (edge id only) ----------------
        const int e = (blockIdx.x - NODE_GS_BLOCKS) * 256 + tid;
        const int dst = eidx[N_EDGES + e];
        const int slot = atomicAdd(&counts[dst], 1);
        if (slot < CAP) bucket[(long)dst * CAP + slot] = e;
    }
}

// ---------------------------------------------------------------------------
// Aggregation: 8 nodes / 256-thread block, 32 lanes per node-group. FiLM
// computed in-kernel lane-parallel (prologue) into LDS; loop body: broadcast
// ds_read of {h',attr} + prefetched ysv gathers ONLY. 4 edges/iter with the
// next 4 gathers in flight (deeper MLP for the L2-miss-bound gather stream).
// ---------------------------------------------------------------------------
__global__ __launch_bounds__(256) void agg_kernel(
    const float* __restrict__ ee, const float* __restrict__ eattr,
    const int* __restrict__ eidx,
    const float* __restrict__ fcw1, const float* __restrict__ fcw2,
    const float* __restrict__ W2s, const float* __restrict__ W2v,
    const unsigned short* __restrict__ ysvh,
    const int* __restrict__ counts, const int* __restrict__ bucket,
    float* __restrict__ out)
{
    __shared__ float hrec[8][32 * 12];  // 12 KB: per group, per slot {h'[8], attr[4]}
    __shared__ float mid[8][256];       // 8 KB

    const int tid = threadIdx.x;
    const int nl = tid >> 5;
    const int u  = tid & 31;
    const int node = blockIdx.x * 8 + nl;
    const float inv_sqrt8 = 0.35355339059327373f;

    // fc2 fragment: f2r[j][q] = fcw2[j*128 + q*32 + u]
    float f2r[8][4];
    #pragma unroll
    for (int j = 0; j < 8; ++j) {
        f2r[j][0] = fcw2[j*128 + u];
        f2r[j][1] = fcw2[j*128 + 32 + u];
        f2r[j][2] = fcw2[j*128 + 64 + u];
        f2r[j][3] = fcw2[j*128 + 96 + u];
    }

    const int cnt = min(counts[node], CAP);
    int e0 = bucket[(long)node * CAP + u];
    const bool dummy = (u >= cnt);
    if (dummy) e0 = 0;
    int s0 = eidx[e0];                  // src for this slot (gather)

    // ---- prologue: lane u computes FiLM h' for its own slot's edge ----
    {
        const float4 ea = ((const float4*)(ee + (long)e0 * 8))[0];
        const float4 eb = ((const float4*)(ee + (long)e0 * 8))[1];
        const float4 at = ((const float4*)eattr)[e0];
        const float eev[8] = {ea.x, ea.y, ea.z, ea.w, eb.x, eb.y, eb.z, eb.w};
        float* hr = hrec[nl] + u * 12;
        float h[8];
        #pragma unroll
        for (int j = 0; j < 8; ++j) {
            float pre = 0.f;
            #pragma unroll
            for (int b = 0; b < 8; ++b) pre += eev[b] * fcw1[b*8 + j];
            pre *= inv_sqrt8;
            const float s = pre / (1.f + __expf(-pre)) * inv_sqrt8;
            h[j] = dummy ? 0.f : s;     // h'=0 kills every term of a dummy slot
        }
        ((float4*)hr)[0] = make_float4(h[0], h[1], h[2], h[3]);
        ((float4*)hr)[1] = make_float4(h[4], h[5], h[6], h[7]);
        ((float4*)hr)[2] = at;
        // no barrier: written and read by the same 32-lane group (wave-sync)
    }

    float msa = 0.f, msb = 0.f;
    float va0 = 0.f, va1 = 0.f, va2 = 0.f;
    float vb0 = 0.f, vb1 = 0.f, vb2 = 0.f;

    #define ACCUM(HA, HB, AT, Y)                                             \
    {                                                                        \
        const float es = __uint_as_float((Y).x << 16);                       \
        const float ex = __uint_as_float((Y).x & 0xffff0000u);               \
        const float ey = __uint_as_float((Y).y << 16);                       \
        const float ez = __uint_as_float((Y).y & 0xffff0000u);               \
        const float hh[8] = {HA.x,HA.y,HA.z,HA.w,HB.x,HB.y,HB.z,HB.w};       \
        float w00=0.f, w01=0.f, w10=0.f, w11=0.f;                            \
        _Pragma("unroll")                                                    \
        for (int j = 0; j < 8; ++j) {                                        \
            w00 += hh[j]*f2r[j][0]; w01 += hh[j]*f2r[j][1];                  \
            w10 += hh[j]*f2r[j][2]; w11 += hh[j]*f2r[j][3];                  \
        }                                                                    \
        const float a0 = AT.x, a1x = AT.y, a1y = AT.z, a1z = AT.w;           \
        msa += w00 * es * a0;                                                \
        msb += w11 * (ex*a1x + ey*a1y + ez*a1z);                             \
        const float t = w01 * es;                                            \
        va0 += t*a1x; va1 += t*a1y; va2 += t*a1z;                            \
        const float s = w10 * a0;                                            \
        vb0 += s*ex; vb1 += s*ey; vb2 += s*ez;                               \
    }

    #define GATHER(SLOT) \
        (*(const uint2*)(ysvh + (long)__shfl(s0, (SLOT), 32) * 128 + u * 4))

    // ---- main loop: 4 edges/iter, next 4 gathers in flight ----
    const int c0 = min(cnt, 32);
    {
        uint2 y0 = GATHER(0), y1 = GATHER(1), y2 = GATHER(2), y3 = GATHER(3);
        for (int k = 0; k < c0; k += 4) {
            const int kn = (k + 4) & 31;            // wrap: dummy-safe
            const uint2 n0 = GATHER(kn);
            const uint2 n1 = GATHER(kn + 1);
            const uint2 n2 = GATHER(kn + 2);
            const uint2 n3 = GATHER(kn + 3);
            const float4* h0p = (const float4*)(hrec[nl] + (k + 0) * 12);
            const float4* h1p = (const float4*)(hrec[nl] + (k + 1) * 12);
            const float4* h2p = (const float4*)(hrec[nl] + (k + 2) * 12);
            const float4* h3p = (const float4*)(hrec[nl] + (k + 3) * 12);
            const float4 A0 = h0p[0], B0 = h0p[1], T0 = h0p[2];
            const float4 A1 = h1p[0], B1 = h1p[1], T1 = h1p[2];
            const float4 A2 = h2p[0], B2 = h2p[1], T2 = h2p[2];
            const float4 A3 = h3p[0], B3 = h3p[1], T3 = h3p[2];
            ACCUM(A0, B0, T0, y0)
            ACCUM(A1, B1, T1, y1)
            ACCUM(A2, B2, T2, y2)
            ACCUM(A3, B3, T3, y3)
            y0 = n0; y1 = n1; y2 = n2; y3 = n3;
        }
    }

    // ---- rare tail (cnt > 32): redundant per-lane FiLM ----
    if (cnt > 32) {
        int be = bucket[(long)node * CAP + 32 + u];
        if (32 + u >= cnt) be = 0;
        for (int k = 32; k < cnt; ++k) {
            const int e = __shfl(be, k - 32, 32);
            const int s = eidx[e];
            const float4 ea = ((const float4*)(ee + (long)e * 8))[0];
            const float4 eb = ((const float4*)(ee + (long)e * 8))[1];
            const float4 at = ((const float4*)eattr)[e];
            const float eev[8] = {ea.x, ea.y, ea.z, ea.w, eb.x, eb.y, eb.z, eb.w};
            float h[8];
            #pragma unroll
            for (int j = 0; j < 8; ++j) {
                float pre = 0.f;
                #pragma unroll
                for (int b = 0; b < 8; ++b) pre += eev[b] * fcw1[b*8 + j];
                pre *= inv_sqrt8;
                h[j] = pre / (1.f + __expf(-pre)) * inv_sqrt8;
            }
            const float4 HA = make_float4(h[0], h[1], h[2], h[3]);
            const float4 HB = make_float4(h[4], h[5], h[6], h[7]);
            const uint2 y = *(const uint2*)(ysvh + (long)s * 128 + u * 4);
            ACCUM(HA, HB, at, y)
        }
    }
    #undef GATHER
    #undef ACCUM

    msb *= 0.5773502691896258f;  // INV_SQRT3

    // ---- lin2 epilogue via mid-LDS transpose (intra-group, no barrier) ----
    float* m = mid[nl];
    m[u]       = msa;
    m[32 + u]  = msb;
    m[64  + u*3 + 0] = va0;  m[64  + u*3 + 1] = va1;  m[64  + u*3 + 2] = va2;
    m[160 + u*3 + 0] = vb0;  m[160 + u*3 + 1] = vb1;  m[160 + u*3 + 2] = vb2;

    float os = 0.f, ov0 = 0.f, ov1 = 0.f, ov2 = 0.f;
    #pragma unroll 8
    for (int q = 0; q < 32; ++q) {
        const float wsa = W2s[q*32 + u];
        const float wsb = W2s[(32 + q)*32 + u];
        os += m[q] * wsa + m[32 + q] * wsb;
        const float wva = W2v[q*32 + u];
        const float wvb = W2v[(32 + q)*32 + u];
        ov0 += m[64 + q*3 + 0] * wva + m[160 + q*3 + 0] * wvb;
        ov1 += m[64 + q*3 + 1] * wva + m[160 + q*3 + 1] * wvb;
        ov2 += m[64 + q*3 + 2] * wva + m[160 + q*3 + 2] * wvb;
    }

    const float sc = 0.03125f;  // (1/sqrt 16) * (1/sqrt 64)
    float* op = out + (long)node * 128;
    op[u]            += os  * sc;
    op[32 + 3*u + 0] += ov0 * sc;
    op[32 + 3*u + 1] += ov1 * sc;
    op[32 + 3*u + 2] += ov2 * sc;
}

extern "C" void kernel_launch(void* const* d_in, const int* in_sizes, int n_in,
                              void* d_out, int out_size, void* d_ws, size_t ws_size,
                              hipStream_t stream) {
    const float* x     = (const float*)d_in[0];
    const float* attr  = (const float*)d_in[1];
    const float* ee    = (const float*)d_in[2];
    const float* eattr = (const float*)d_in[3];
    const int*   eidx  = (const int*)  d_in[4];
    const float* W1s   = (const float*)d_in[5];
    const float* W1v   = (const float*)d_in[6];
    const float* fcw1  = (const float*)d_in[7];
    const float* fcw2  = (const float*)d_in[8];
    const float* W2s   = (const float*)d_in[9];
    const float* W2v   = (const float*)d_in[10];
    const float* Wscs  = (const float*)d_in[11];
    const float* Wscv  = (const float*)d_in[12];

    float* out = (float*)d_out;

    // workspace layout (16-B aligned)
    unsigned short* ysvh = (unsigned short*)d_ws;            // 50000*128 bf16 = 12.8 MB
    int*   counts = (int*)(ysvh + (long)N_NODES * 128);      // 50000 i32
    int*   bucket = counts + N_NODES;                        // 50000*64 i32 = 12.8 MB

    hipMemsetAsync(counts, 0, N_NODES * sizeof(int), stream);
    prep_kernel<<<NODE_GS_BLOCKS + BUCKET_BLOCKS, 256, 0, stream>>>(
        x, attr, W1s, W1v, Wscs, Wscv, eidx, counts, bucket, ysvh, out);
    agg_kernel<<<N_NODES/8, 256, 0, stream>>>(ee, eattr, eidx, fcw1, fcw2,
                                              W2s, W2v, ysvh, counts, bucket, out);
}